// Round 6
// baseline (318.866 us; speedup 1.0000x reference)
//
#include <hip/hip_runtime.h>
#include <stdint.h>
#include <math.h>

#define BB 2
#define SS 2048
#define HH 2048
#define NH 16
#define KVH 4
#define HD 128
#define BSZ (BB*SS)      // 4096
#define QW (NH*HD)       // 2048
#define KVW (KVH*HD)     // 512

typedef __attribute__((ext_vector_type(8))) short s16x8;   // 8 bf16 = 4 VGPRs
typedef __attribute__((ext_vector_type(4))) float f32x4;   // MFMA C/D

typedef const unsigned int __attribute__((address_space(1)))* gas_ptr;
typedef unsigned int __attribute__((address_space(3)))* las_ptr;

__device__ __forceinline__ unsigned short f2b(float x) {
    unsigned u = __builtin_bit_cast(unsigned, x);
    unsigned r = u + 0x7fffu + ((u >> 16) & 1u);   // round-to-nearest-even
    return (unsigned short)(r >> 16);
}
__device__ __forceinline__ float b2f(unsigned short h) {
    unsigned u = ((unsigned)h) << 16;
    return __builtin_bit_cast(float, u);
}

// async global->LDS, 16B per lane; LDS dest = wave-uniform base + lane*16
__device__ __forceinline__ void gload_lds16(const void* g, void* l) {
    __builtin_amdgcn_global_load_lds((gas_ptr)g, (las_ptr)l, 16, 0, 0);
}

// ---------------------------------------------------------------------------
// bf16 MFMA GEMM tile body (m97 structure): C(128x128) = A(128xK) * Bt(128xK)^T
// ---------------------------------------------------------------------------
__device__ __forceinline__ void mfma_gemm_tile(
    const unsigned short* __restrict__ A,
    const unsigned short* __restrict__ Bt,
    int m0, int c0, f32x4 acc[4][4],
    unsigned short* As, unsigned short* Bs)
{
    const int tid  = threadIdx.x;
    const int lane = tid & 63, wave = tid >> 6;
    const int quad = lane >> 4, l15 = lane & 15;
    const int mh = wave >> 1, nh = wave & 1;
    const int srow = lane >> 2;        // staging row within 16-row chunk
    const int sk   = (lane & 3) * 8;   // staging k offset (elements)

#pragma unroll
    for (int i = 0; i < 4; ++i)
#pragma unroll
        for (int j = 0; j < 4; ++j) acc[i][j] = (f32x4){0.f, 0.f, 0.f, 0.f};

    for (int k0 = 0; k0 < HH; k0 += 32) {
        __syncthreads();
#pragma unroll
        for (int j = 0; j < 2; ++j) {
            int chunk = wave * 2 + j;            // 0..7, 16 rows each
            int row = chunk * 16 + srow;
            gload_lds16(A  + (size_t)(m0 + row) * HH + k0 + sk, As + chunk * 512);
            gload_lds16(Bt + (size_t)(c0 + row) * HH + k0 + sk, Bs + chunk * 512);
        }
        __syncthreads();

        s16x8 af[4], bf[4];
#pragma unroll
        for (int t = 0; t < 4; ++t) {
            af[t] = *(const s16x8*)(As + (mh * 64 + t * 16 + l15) * 32 + quad * 8);
            bf[t] = *(const s16x8*)(Bs + (nh * 64 + t * 16 + l15) * 32 + quad * 8);
        }
#pragma unroll
        for (int mt = 0; mt < 4; ++mt)
#pragma unroll
            for (int nt = 0; nt < 4; ++nt)
                acc[mt][nt] = __builtin_amdgcn_mfma_f32_16x16x32_bf16(
                    af[mt], bf[nt], acc[mt][nt], 0, 0, 0);
    }
}

__global__ __launch_bounds__(256) void gemm_qkv(
    const unsigned short* __restrict__ Ah,
    const unsigned short* __restrict__ Wqt,
    const unsigned short* __restrict__ Wkt,
    const unsigned short* __restrict__ Wvt,
    unsigned short* __restrict__ Qb,
    unsigned short* __restrict__ Kb,
    unsigned short* __restrict__ Vb)
{
    __shared__ __align__(16) unsigned short As[128 * 32];
    __shared__ __align__(16) unsigned short Bs[128 * 32];
    const int nblk = blockIdx.x * 128;   // 0..3071 over [Q|K|V]
    const int m0 = blockIdx.y * 128;
    const unsigned short* Bt;
    unsigned short* C;
    int c0, ldc;
    if (nblk < QW)            { Bt = Wqt; C = Qb; c0 = nblk;            ldc = QW;  }
    else if (nblk < QW + KVW) { Bt = Wkt; C = Kb; c0 = nblk - QW;       ldc = KVW; }
    else                      { Bt = Wvt; C = Vb; c0 = nblk - QW - KVW; ldc = KVW; }

    f32x4 acc[4][4];
    mfma_gemm_tile(Ah, Bt, m0, c0, acc, As, Bs);

    const int lane = threadIdx.x & 63, wave = threadIdx.x >> 6;
    const int quad = lane >> 4, l15 = lane & 15;
    const int mh = wave >> 1, nh = wave & 1;
#pragma unroll
    for (int mt = 0; mt < 4; ++mt)
#pragma unroll
        for (int nt = 0; nt < 4; ++nt)
#pragma unroll
            for (int r = 0; r < 4; ++r) {
                int row = m0 + mh * 64 + mt * 16 + quad * 4 + r;   // m89 C/D layout
                int col = c0 + nh * 64 + nt * 16 + l15;
                C[(size_t)row * ldc + col] = f2b(acc[mt][nt][r]);
            }
}

__global__ __launch_bounds__(256) void gemm_out(
    const unsigned short* __restrict__ ctx,
    const unsigned short* __restrict__ Wot,
    float* __restrict__ out)
{
    __shared__ __align__(16) unsigned short As[128 * 32];
    __shared__ __align__(16) unsigned short Bs[128 * 32];
    const int c0 = blockIdx.x * 128;
    const int m0 = blockIdx.y * 128;

    f32x4 acc[4][4];
    mfma_gemm_tile(ctx, Wot, m0, c0, acc, As, Bs);

    const int lane = threadIdx.x & 63, wave = threadIdx.x >> 6;
    const int quad = lane >> 4, l15 = lane & 15;
    const int mh = wave >> 1, nh = wave & 1;
#pragma unroll
    for (int mt = 0; mt < 4; ++mt)
#pragma unroll
        for (int nt = 0; nt < 4; ++nt)
#pragma unroll
            for (int r = 0; r < 4; ++r) {
                int row = m0 + mh * 64 + mt * 16 + quad * 4 + r;
                int col = c0 + nh * 64 + nt * 16 + l15;
                out[(size_t)row * HH + col] = acc[mt][nt][r];
            }
}

// ---------------------------------------------------------------------------
// conversions
// ---------------------------------------------------------------------------
__global__ __launch_bounds__(256) void convert_bf16(const float* __restrict__ in,
                                                    unsigned short* __restrict__ out,
                                                    int n)
{
    int i = (blockIdx.x * 256 + threadIdx.x) * 4;
    if (i >= n) return;
    float4 v = *(const float4*)(in + i);
    ushort4 o = make_ushort4(f2b(v.x), f2b(v.y), f2b(v.z), f2b(v.w));
    *(ushort4*)(out + i) = o;
}

// all four weight transposes fused: fp32 [K=2048][N] -> bf16 [N][2048]
__global__ __launch_bounds__(256) void transpose_all(
    const float* __restrict__ Wq, const float* __restrict__ Wk,
    const float* __restrict__ Wv, const float* __restrict__ Wo,
    unsigned short* __restrict__ Wqt, unsigned short* __restrict__ Wkt,
    unsigned short* __restrict__ Wvt, unsigned short* __restrict__ Wot)
{
    const int z = blockIdx.z;
    const float* in;
    unsigned short* out;
    int N;
    if (z == 0)      { in = Wq; out = Wqt; N = QW;  }
    else if (z == 1) { in = Wk; out = Wkt; N = KVW; }
    else if (z == 2) { in = Wv; out = Wvt; N = KVW; }
    else             { in = Wo; out = Wot; N = HH;  }
    const int n0 = blockIdx.x * 32;
    if (n0 >= N) return;
    const int k0 = blockIdx.y * 32;

    __shared__ float t[32][33];
    const int c = threadIdx.x & 31, r = threadIdx.x >> 5;   // r = 0..7
#pragma unroll
    for (int j = 0; j < 4; ++j)
        t[r + j * 8][c] = in[(size_t)(k0 + r + j * 8) * N + n0 + c];
    __syncthreads();
#pragma unroll
    for (int j = 0; j < 4; ++j)
        out[(size_t)(n0 + r + j * 8) * HH + k0 + c] = f2b(t[c][r + j * 8]);
}

// bf16 V [b*SS+s][KVW] -> V^T [b*KVW + c][SS]  (per-batch transpose)
__global__ __launch_bounds__(256) void vtrans_bf16(const unsigned short* __restrict__ Vb,
                                                   unsigned short* __restrict__ Vtg)
{
    __shared__ unsigned short t[32][33];
    const int s0 = blockIdx.x * 32, c0 = blockIdx.y * 32, b = blockIdx.z;
    const int cc = threadIdx.x & 31, r = threadIdx.x >> 5;   // r = 0..7
#pragma unroll
    for (int j = 0; j < 4; ++j)
        t[r + j * 8][cc] = Vb[(size_t)(b * SS + s0 + r + j * 8) * KVW + c0 + cc];
    __syncthreads();
#pragma unroll
    for (int j = 0; j < 4; ++j)
        Vtg[(size_t)(b * KVW + c0 + r + j * 8) * SS + s0 + cc] = t[cc][r + j * 8];
}

// ---------------------------------------------------------------------------
// RoPE on K only (Q's RoPE is fused into attn's register prologue)
// ---------------------------------------------------------------------------
__global__ __launch_bounds__(256) void rope_k(unsigned short* __restrict__ Kb)
{
    int idx = blockIdx.x * 256 + threadIdx.x;   // BSZ*KVH*64 total
    int j = idx & 63;
    int t = idx >> 6;
    int hh = t & (KVH - 1);
    int bs = t >> 2;
    int s = bs & (SS - 1);
    float inv = exp2f(-0.2076205063f * (float)j);   // 10000^(-j/64)
    float ang = (float)s * inv;
    float c = __cosf(ang), sn = __sinf(ang);
    size_t base = (size_t)bs * KVW + (size_t)hh * HD;
    float x1 = b2f(Kb[base + j]);
    float x2 = b2f(Kb[base + j + 64]);
    Kb[base + j]      = f2b(x1 * c - x2 * sn);
    Kb[base + j + 64] = f2b(x2 * c + x1 * sn);
}

// ---------------------------------------------------------------------------
// Flash attention, bf16 MFMA, GQA-shared K/V staging.
// Block = (b, kvh, 32-row q-group p); 4 waves = the 4 q-heads of the kv group,
// each wave 32 q-rows (2 row-tiles of 16) at rows [32p, 32p+32).
// K-tile 128 (halves barrier count); processed as 2 halves of 64 kv to keep
// sc register footprint down; fully-masked halves skipped (wave-uniform).
// Q RoPE + 1/sqrt(HD) applied in the register prologue (Qb is raw GEMM out).
// Fixed-max softmax exp(s-10) (exact); l via ones-B MFMA. K LDS [kr][128]
// XOR-swizzled, V^T LDS [d][128] XOR-swizzled; P via per-wave LDS buffer
// reused across row-tiles (WAR safe: wave DS ops are ordered). Register
// prefetch of tile kt+1. Heavy blocks (large p) dispatch first.
// ---------------------------------------------------------------------------
__global__ __launch_bounds__(256, 2) void attn_mfma(
    const unsigned short* __restrict__ Qb,
    const unsigned short* __restrict__ Kb,
    const unsigned short* __restrict__ Vtg,
    unsigned short* __restrict__ ctx)
{
    const int bk  = blockIdx.x;            // 0..7 = b*KVH + kvh
    const int b   = bk >> 2, kvh = bk & 3;
    const int p   = 63 - (int)blockIdx.y;  // heavy first
    const int q0  = p * 32;
    const int rowmax = q0 + 31;
    const int tid = threadIdx.x;
    const int lane = tid & 63, wave = tid >> 6;   // wave = head-in-group
    const int h = kvh * 4 + wave;
    const int quad = lane >> 4, l15 = lane & 15;

    __shared__ __align__(16) unsigned short Ks[128 * 128];   // 32 KB
    __shared__ __align__(16) unsigned short Vt[128 * 128];   // 32 KB
    __shared__ __align__(16) unsigned short Ps[4][16 * 72];  // 9 KB, per-wave

    const int srow = tid >> 4;             // 0..15
    const int sc8  = tid & 15;             // 16B chunk index in a 128-elem row

    const unsigned short* Kbase = Kb  + (size_t)b * SS * KVW + kvh * HD;
    const unsigned short* Vbase = Vtg + (size_t)(b * KVW + kvh * HD) * SS;

    // ---- Q frags + fused RoPE + scale ----
    s16x8 qf[2][4];
#pragma unroll
    for (int rt = 0; rt < 2; ++rt) {
        const unsigned short* qrow =
            Qb + (size_t)(b * SS + q0 + rt * 16 + l15) * QW + h * HD;
#pragma unroll
        for (int dc = 0; dc < 4; ++dc)
            qf[rt][dc] = *(const s16x8*)(qrow + dc * 32 + quad * 8);
    }
#pragma unroll
    for (int rt = 0; rt < 2; ++rt) {
        const float pos = (float)(q0 + rt * 16 + l15);
#pragma unroll
        for (int dcp = 0; dcp < 2; ++dcp)
#pragma unroll
            for (int i = 0; i < 8; ++i) {
                int jj = dcp * 32 + quad * 8 + i;
                float inv = exp2f(-0.2076205063f * (float)jj);
                float ang = pos * inv;
                float sn, cs;
                __sincosf(ang, &sn, &cs);
                float x1 = b2f((unsigned short)qf[rt][dcp][i]);
                float x2 = b2f((unsigned short)qf[rt][dcp + 2][i]);
                qf[rt][dcp][i]     = (short)f2b((x1 * cs - x2 * sn) * 0.08838834764831845f);
                qf[rt][dcp + 2][i] = (short)f2b((x2 * cs + x1 * sn) * 0.08838834764831845f);
            }
    }

    f32x4 oacc[2][8];
#pragma unroll
    for (int rt = 0; rt < 2; ++rt)
#pragma unroll
        for (int i = 0; i < 8; ++i) oacc[rt][i] = (f32x4){0.f, 0.f, 0.f, 0.f};
    f32x4 lacc[2] = {(f32x4){0.f,0.f,0.f,0.f}, (f32x4){0.f,0.f,0.f,0.f}};

    const s16x8 vone = {0x3F80, 0x3F80, 0x3F80, 0x3F80,
                        0x3F80, 0x3F80, 0x3F80, 0x3F80};   // bf16 1.0 x8

    // prime register prefetch: 8 K chunks + 8 V^T chunks (16B each)
    s16x8 kpre[8], vpre[8];
#pragma unroll
    for (int u = 0; u < 8; ++u) {
        kpre[u] = *(const s16x8*)(Kbase + (size_t)(u * 16 + srow) * KVW + sc8 * 8);
        vpre[u] = *(const s16x8*)(Vbase + (size_t)(u * 16 + srow) * SS + sc8 * 8);
    }

    const int nkt = (p >> 2) + 1;
    for (int kt = 0; kt < nkt; ++kt) {
        const int k0 = kt * 128;
        __syncthreads();   // previous iteration's Ks/Vt readers done

        // store prefetched tile (swizzle: chunk ^ (row&15); row&15 == srow)
#pragma unroll
        for (int u = 0; u < 8; ++u) {
            *(s16x8*)(Ks + (u * 16 + srow) * 128 + ((sc8 ^ srow) * 8)) = kpre[u];
            *(s16x8*)(Vt + (u * 16 + srow) * 128 + ((sc8 ^ srow) * 8)) = vpre[u];
        }
        __syncthreads();

        // issue next tile's global loads
        if (kt + 1 < nkt) {
            const int kn = k0 + 128;
#pragma unroll
            for (int u = 0; u < 8; ++u) {
                kpre[u] = *(const s16x8*)(Kbase + (size_t)(kn + u * 16 + srow) * KVW + sc8 * 8);
                vpre[u] = *(const s16x8*)(Vbase + (size_t)(u * 16 + srow) * SS + kn + sc8 * 8);
            }
        }

#pragma unroll
        for (int half = 0; half < 2; ++half) {
            const int kh0 = k0 + half * 64;
            if (kh0 > rowmax) break;   // fully-masked half (block-uniform)

            // S = Q K^T over this 64-kv half; kf shared across row-tiles
            f32x4 sc[2][4];
#pragma unroll
            for (int rt = 0; rt < 2; ++rt)
#pragma unroll
                for (int tk = 0; tk < 4; ++tk) sc[rt][tk] = (f32x4){0.f,0.f,0.f,0.f};
#pragma unroll
            for (int tk = 0; tk < 4; ++tk) {
#pragma unroll
                for (int dc = 0; dc < 4; ++dc) {
                    s16x8 kf = *(const s16x8*)(Ks + (half * 64 + tk * 16 + l15) * 128
                                                  + (((dc * 4 + quad) ^ l15) * 8));
                    sc[0][tk] = __builtin_amdgcn_mfma_f32_16x16x32_bf16(qf[0][dc], kf, sc[0][tk], 0, 0, 0);
                    sc[1][tk] = __builtin_amdgcn_mfma_f32_16x16x32_bf16(qf[1][dc], kf, sc[1][tk], 0, 0, 0);
                }
            }

            // fixed-max softmax + P to per-wave LDS (buffer reused per rt)
            unsigned short* pw = &Ps[wave][0];
            s16x8 pf[2][2];
#pragma unroll
            for (int rt = 0; rt < 2; ++rt) {
                const int rowbase = q0 + rt * 16;
                const bool straddle = (kh0 + 63 > rowbase);
#pragma unroll
                for (int tk = 0; tk < 4; ++tk) {
                    const int col = kh0 + tk * 16 + l15;
#pragma unroll
                    for (int r = 0; r < 4; ++r) {
                        float pv = __expf(sc[rt][tk][r] - 10.0f);
                        if (straddle && col > rowbase + quad * 4 + r) pv = 0.f;
                        pw[(quad * 4 + r) * 72 + tk * 16 + l15] = f2b(pv);
                    }
                }
#pragma unroll
                for (int kc = 0; kc < 2; ++kc)
                    pf[rt][kc] = *(const s16x8*)(pw + l15 * 72 + kc * 32 + quad * 8);
            }

            // l row-sums via ones B-frag
#pragma unroll
            for (int rt = 0; rt < 2; ++rt)
#pragma unroll
                for (int kc = 0; kc < 2; ++kc)
                    lacc[rt] = __builtin_amdgcn_mfma_f32_16x16x32_bf16(pf[rt][kc], vone, lacc[rt], 0, 0, 0);

            // PV: vf shared across row-tiles
#pragma unroll
            for (int dt = 0; dt < 8; ++dt) {
#pragma unroll
                for (int kc = 0; kc < 2; ++kc) {
                    s16x8 vf = *(const s16x8*)(Vt + (dt * 16 + l15) * 128
                                                  + (((half * 8 + kc * 4 + quad) ^ l15) * 8));
                    oacc[0][dt] = __builtin_amdgcn_mfma_f32_16x16x32_bf16(pf[0][kc], vf, oacc[0][dt], 0, 0, 0);
                    oacc[1][dt] = __builtin_amdgcn_mfma_f32_16x16x32_bf16(pf[1][kc], vf, oacc[1][dt], 0, 0, 0);
                }
            }
        }
    }

    // epilogue: O / l
#pragma unroll
    for (int rt = 0; rt < 2; ++rt) {
        float linv[4];
#pragma unroll
        for (int r = 0; r < 4; ++r) linv[r] = 1.0f / lacc[rt][r];
#pragma unroll
        for (int dt = 0; dt < 8; ++dt)
#pragma unroll
            for (int r = 0; r < 4; ++r) {
                int row = b * SS + q0 + rt * 16 + quad * 4 + r;
                ctx[(size_t)row * QW + h * HD + dt * 16 + l15] =
                    f2b(oacc[rt][dt][r] * linv[r]);
            }
    }
}

// ---------------------------------------------------------------------------
extern "C" void kernel_launch(void* const* d_in, const int* in_sizes, int n_in,
                              void* d_out, int out_size, void* d_ws, size_t ws_size,
                              hipStream_t stream)
{
    const float* hidden = (const float*)d_in[0];
    const float* Wq = (const float*)d_in[1];
    const float* Wk = (const float*)d_in[2];
    const float* Wv = (const float*)d_in[3];
    const float* Wo = (const float*)d_in[4];
    float* out = (float*)d_out;

    // workspace layout (bf16 elements), ~88 MB total
    unsigned short* Ah  = (unsigned short*)d_ws;                 // 4096*2048
    unsigned short* Wqt = Ah  + (size_t)BSZ * HH;                // 2048*2048
    unsigned short* Wkt = Wqt + (size_t)QW * HH;                 // 512*2048
    unsigned short* Wvt = Wkt + (size_t)KVW * HH;                // 512*2048
    unsigned short* Wot = Wvt + (size_t)KVW * HH;                // 2048*2048
    unsigned short* Qb  = Wot + (size_t)HH * QW;                 // 4096*2048
    unsigned short* Kb  = Qb  + (size_t)BSZ * QW;                // 4096*512
    unsigned short* Vb  = Kb  + (size_t)BSZ * KVW;               // 4096*512
    unsigned short* ctx = Vb  + (size_t)BSZ * KVW;               // 4096*2048
    unsigned short* Vtg = ctx + (size_t)BSZ * QW;                // 4096*512 (V^T)

    // 1. dtype conversions (fused transposes)
    convert_bf16<<<(BSZ * HH / 4 + 255) / 256, 256, 0, stream>>>(hidden, Ah, BSZ * HH);
    transpose_all<<<dim3(64, 64, 4), 256, 0, stream>>>(Wq, Wk, Wv, Wo,
                                                       Wqt, Wkt, Wvt, Wot);

    // 2. fused QKV GEMM (bf16 MFMA)
    gemm_qkv<<<dim3((QW + 2 * KVW) / 128, BSZ / 128), 256, 0, stream>>>(
        Ah, Wqt, Wkt, Wvt, Qb, Kb, Vb);

    // 3. V^T for attention's PV B-operand (s-contiguous rows)
    vtrans_bf16<<<dim3(SS / 32, KVW / 32, BB), 256, 0, stream>>>(Vb, Vtg);

    // 4. RoPE on K only (Q RoPE fused into attn)
    rope_k<<<(BSZ * KVH * 64) / 256, 256, 0, stream>>>(Kb);

    // 5. flash attention (bf16 MFMA, GQA-shared staging)
    attn_mfma<<<dim3(BB * KVH, SS / 32), 256, 0, stream>>>(Qb, Kb, Vtg, ctx);

    // 6. out-projection
    gemm_out<<<dim3(HH / 128, BSZ / 128), 256, 0, stream>>>(ctx, Wot, out);
}